// Round 1
// baseline (316.153 us; speedup 1.0000x reference)
//
#include <hip/hip_runtime.h>
#include <hip/hip_bf16.h>

typedef __attribute__((ext_vector_type(8))) short bf16x8;
typedef __attribute__((ext_vector_type(4))) float f32x4;
typedef unsigned short u16;

#define DIMC 1024
#define NHEAD 16
#define HDIM 64
#define NB 4
#define NQ 4096
#define NS 512

__device__ __forceinline__ u16 f2bf(float f) {
  __hip_bfloat16 h = __float2bfloat16(f);
  return *reinterpret_cast<u16*>(&h);
}

__device__ __forceinline__ void gload_lds16(const void* g, void* s) {
  __builtin_amdgcn_global_load_lds(
      (const __attribute__((address_space(1))) void*)g,
      (__attribute__((address_space(3))) void*)s, 16, 0, 0);
}

// ---------------- conversion kernels ----------------

__global__ void cvt_kernel(const float* __restrict__ in, u16* __restrict__ out, int n4) {
  // n4 = n/4
  int stride = gridDim.x * blockDim.x;
  for (int i = blockIdx.x * blockDim.x + threadIdx.x; i < n4; i += stride) {
    float4 v = *(const float4*)(in + (size_t)i * 4);
    ushort4 o;
    o.x = f2bf(v.x); o.y = f2bf(v.y); o.z = f2bf(v.z); o.w = f2bf(v.w);
    *(ushort4*)(out + (size_t)i * 4) = o;
  }
}

// W [K][N] f32 -> WT [N][K] bf16
__global__ void transpose_cvt_kernel(const float* __restrict__ W, u16* __restrict__ WT,
                                     int K, int N) {
  __shared__ float t[32][33];
  const int bx = blockIdx.x * 32;  // n base
  const int by = blockIdx.y * 32;  // k base
  const int tx = threadIdx.x & 31, ty = threadIdx.x >> 5;  // ty 0..7
#pragma unroll
  for (int i = 0; i < 32; i += 8)
    t[ty + i][tx] = W[(size_t)(by + ty + i) * N + bx + tx];
  __syncthreads();
#pragma unroll
  for (int i = 0; i < 32; i += 8)
    WT[(size_t)(bx + ty + i) * K + by + tx] = f2bf(t[tx][ty + i]);
}

__global__ void mask_kernel(const int* __restrict__ m, float* __restrict__ mf, int n) {
  int i = blockIdx.x * blockDim.x + threadIdx.x;
  if (i < n) mf[i] = m[i] ? -1e30f : 0.0f;
}

// ---------------- bf16 GEMM: C = A[M][K] * (BT[N][K])^T + bias ----------------
// MODE 0: C0 = bf16 [M][N] (Q)
// MODE 1: KV scatter: C0 = K [b][h][s][d] bf16; C1 = VT [b][h][d][s] bf16
// MODE 2: C0 = f32 [M][N] (final out)

template<int MODE>
__launch_bounds__(256)
__global__ void gemm_bt(const u16* __restrict__ A, const u16* __restrict__ BT,
                        const float* __restrict__ bias, void* __restrict__ C0,
                        void* __restrict__ C1, int M, int N, int K) {
  __shared__ __align__(16) u16 As[128 * 32];
  __shared__ __align__(16) u16 Bs[128 * 32];
  const int tid = threadIdx.x;
  const int w = tid >> 6, l = tid & 63;
  const int wr = w >> 1, wc = w & 1;
  const int fr = l & 15, fhi = l >> 4;
  const int m0 = blockIdx.y * 128, n0 = blockIdx.x * 128;

  const f32x4 fz = {0.f, 0.f, 0.f, 0.f};
  f32x4 acc[4][4];
#pragma unroll
  for (int mt = 0; mt < 4; mt++)
#pragma unroll
    for (int nt = 0; nt < 4; nt++) acc[mt][nt] = fz;

  // staging: flat byte offset within 8KB tile; 2 instrs/wave of 1KB each
  const int f0 = w * 2048 + l * 16;
  const int f1 = f0 + 1024;
  const int ar0 = f0 >> 6, ac0 = (f0 & 63) >> 1;
  const int ar1 = f1 >> 6, ac1 = (f1 & 63) >> 1;
  const u16* Ag0 = A + (size_t)(m0 + ar0) * K + ac0;
  const u16* Ag1 = A + (size_t)(m0 + ar1) * K + ac1;
  const u16* Bg0 = BT + (size_t)(n0 + ar0) * K + ac0;
  const u16* Bg1 = BT + (size_t)(n0 + ar1) * K + ac1;

  for (int k0 = 0; k0 < K; k0 += 32) {
    gload_lds16(Ag0 + k0, &As[w * 1024]);
    gload_lds16(Ag1 + k0, &As[w * 1024 + 512]);
    gload_lds16(Bg0 + k0, &Bs[w * 1024]);
    gload_lds16(Bg1 + k0, &Bs[w * 1024 + 512]);
    __syncthreads();

    bf16x8 a[4], b[4];
#pragma unroll
    for (int t = 0; t < 4; t++) {
      a[t] = *(const bf16x8*)&As[(wr * 64 + t * 16 + fr) * 32 + fhi * 8];
      b[t] = *(const bf16x8*)&Bs[(wc * 64 + t * 16 + fr) * 32 + fhi * 8];
    }
#pragma unroll
    for (int mt = 0; mt < 4; mt++)
#pragma unroll
      for (int nt = 0; nt < 4; nt++)
        acc[mt][nt] = __builtin_amdgcn_mfma_f32_16x16x32_bf16(a[mt], b[nt], acc[mt][nt], 0, 0, 0);
    __syncthreads();
  }

#pragma unroll
  for (int mt = 0; mt < 4; mt++) {
#pragma unroll
    for (int nt = 0; nt < 4; nt++) {
      const int col = n0 + wc * 64 + nt * 16 + fr;
      const float bv = bias[col];
#pragma unroll
      for (int r = 0; r < 4; r++) {
        const int row = m0 + wr * 64 + mt * 16 + fhi * 4 + r;
        const float v = acc[mt][nt][r] + bv;
        if (MODE == 0) {
          ((u16*)C0)[(size_t)row * N + col] = f2bf(v);
        } else if (MODE == 1) {
          const int b = row >> 9, s = row & 511;
          if (col < 1024) {
            const int h = col >> 6, d = col & 63;
            ((u16*)C0)[(((size_t)(b * 16 + h)) * 512 + s) * 64 + d] = f2bf(v);
          } else {
            const int c2 = col - 1024;
            const int h = c2 >> 6, d = c2 & 63;
            ((u16*)C1)[(((size_t)(b * 16 + h)) * 64 + d) * 512 + s] = f2bf(v);
          }
        } else {
          ((float*)C0)[(size_t)row * N + col] = v;
        }
      }
    }
  }
}

// ---------------- fused attention ----------------
// Q bf16 [16384][1024]; K bf16 [bh][512][64]; VT bf16 [bh][64][512];
// maskf f32 [b][512]; O bf16 [16384][1024]
__launch_bounds__(256)
__global__ void attn_kernel(const u16* __restrict__ Q, const u16* __restrict__ Kb,
                            const u16* __restrict__ VT, const float* __restrict__ maskf,
                            u16* __restrict__ O) {
  __shared__ __align__(16) u16 Ks[64 * 64];
  __shared__ __align__(16) u16 Vs[64 * 64];
  __shared__ __align__(16) u16 Ps[4 * 32 * 64];
  const int tid = threadIdx.x, w = tid >> 6, l = tid & 63;
  const int fr = l & 15, fhi = l >> 4;
  const int bh = blockIdx.y;
  const int b = bh >> 4, h = bh & 15;
  const int rowbase = b * NQ + blockIdx.x * 128 + w * 32;  // row in [0,16384)

  // Q fragments (held in registers for the whole kernel)
  bf16x8 qf[2][2];
#pragma unroll
  for (int mt = 0; mt < 2; mt++)
#pragma unroll
    for (int kk = 0; kk < 2; kk++)
      qf[mt][kk] = *(const bf16x8*)&Q[(size_t)(rowbase + mt * 16 + fr) * DIMC +
                                      h * 64 + kk * 32 + fhi * 8];

  const u16* Kg = Kb + (size_t)bh * NS * HDIM;  // [512][64]
  const u16* Vg = VT + (size_t)bh * HDIM * NS;  // [64][512]
  const float* mrow = maskf + b * NS;

  const f32x4 fz = {0.f, 0.f, 0.f, 0.f};
  float m_run[2][4], l_run[2][4];
  f32x4 o_acc[2][4];
#pragma unroll
  for (int mt = 0; mt < 2; mt++)
#pragma unroll
    for (int r = 0; r < 4; r++) {
      m_run[mt][r] = -1e30f;
      l_run[mt][r] = 0.f;
      o_acc[mt][r] = fz;
    }

  // staging offsets (8KB tile, 2KB per wave => 2 instrs of 1KB)
  const int f0 = w * 2048 + l * 16;
  const int f1 = f0 + 1024;
  const int sr0 = f0 >> 7, sc0 = (f0 & 127) >> 1;  // row, elem-col (128B rows)
  const int sr1 = f1 >> 7, sc1 = (f1 & 127) >> 1;

  for (int sc = 0; sc < NS; sc += 64) {
    gload_lds16(Kg + (size_t)(sc + sr0) * 64 + sc0, &Ks[w * 1024]);
    gload_lds16(Kg + (size_t)(sc + sr1) * 64 + sc1, &Ks[w * 1024 + 512]);
    gload_lds16(Vg + (size_t)sr0 * NS + sc + sc0, &Vs[w * 1024]);
    gload_lds16(Vg + (size_t)sr1 * NS + sc + sc1, &Vs[w * 1024 + 512]);
    __syncthreads();

    // S = Q K^T for this 128x64 block (per wave: 32 q-rows x 64 s-cols)
    f32x4 sacc[2][4];
#pragma unroll
    for (int mt = 0; mt < 2; mt++)
#pragma unroll
      for (int sn = 0; sn < 4; sn++) sacc[mt][sn] = fz;
#pragma unroll
    for (int sn = 0; sn < 4; sn++) {
      const bf16x8 kf0 = *(const bf16x8*)&Ks[(sn * 16 + fr) * 64 + fhi * 8];
      const bf16x8 kf1 = *(const bf16x8*)&Ks[(sn * 16 + fr) * 64 + 32 + fhi * 8];
#pragma unroll
      for (int mt = 0; mt < 2; mt++) {
        sacc[mt][sn] = __builtin_amdgcn_mfma_f32_16x16x32_bf16(qf[mt][0], kf0, sacc[mt][sn], 0, 0, 0);
        sacc[mt][sn] = __builtin_amdgcn_mfma_f32_16x16x32_bf16(qf[mt][1], kf1, sacc[mt][sn], 0, 0, 0);
      }
    }

    // scale + mask
    float p[2][4][4];
    float mv[4];
#pragma unroll
    for (int sn = 0; sn < 4; sn++) mv[sn] = mrow[sc + sn * 16 + fr];
#pragma unroll
    for (int mt = 0; mt < 2; mt++)
#pragma unroll
      for (int sn = 0; sn < 4; sn++)
#pragma unroll
        for (int r = 0; r < 4; r++)
          p[mt][sn][r] = sacc[mt][sn][r] * 0.125f + mv[sn];

    // online softmax update
#pragma unroll
    for (int mt = 0; mt < 2; mt++) {
#pragma unroll
      for (int r = 0; r < 4; r++) {
        float cm = fmaxf(fmaxf(p[mt][0][r], p[mt][1][r]), fmaxf(p[mt][2][r], p[mt][3][r]));
#pragma unroll
        for (int x = 1; x < 16; x <<= 1) cm = fmaxf(cm, __shfl_xor(cm, x));
        const float mnew = fmaxf(m_run[mt][r], cm);
        const float rscale = __expf(m_run[mt][r] - mnew);
        m_run[mt][r] = mnew;
        float rsum = 0.f;
#pragma unroll
        for (int sn = 0; sn < 4; sn++) {
          p[mt][sn][r] = __expf(p[mt][sn][r] - mnew);
          rsum += p[mt][sn][r];
        }
#pragma unroll
        for (int x = 1; x < 16; x <<= 1) rsum += __shfl_xor(rsum, x);
        l_run[mt][r] = l_run[mt][r] * rscale + rsum;
#pragma unroll
        for (int dn = 0; dn < 4; dn++) o_acc[mt][dn][r] *= rscale;
      }
    }

    // P -> per-wave LDS (re-fragment for PV)
    u16* Pw = &Ps[w * 2048];
#pragma unroll
    for (int mt = 0; mt < 2; mt++)
#pragma unroll
      for (int sn = 0; sn < 4; sn++)
#pragma unroll
        for (int r = 0; r < 4; r++)
          Pw[(mt * 16 + fhi * 4 + r) * 64 + sn * 16 + fr] = f2bf(p[mt][sn][r]);
    asm volatile("s_waitcnt lgkmcnt(0)" ::: "memory");

    // O += P V
#pragma unroll
    for (int kk = 0; kk < 2; kk++) {
      bf16x8 pf[2];
#pragma unroll
      for (int mt = 0; mt < 2; mt++)
        pf[mt] = *(const bf16x8*)&Pw[(mt * 16 + fr) * 64 + kk * 32 + fhi * 8];
#pragma unroll
      for (int dn = 0; dn < 4; dn++) {
        const bf16x8 vf = *(const bf16x8*)&Vs[(dn * 16 + fr) * 64 + kk * 32 + fhi * 8];
#pragma unroll
        for (int mt = 0; mt < 2; mt++)
          o_acc[mt][dn] = __builtin_amdgcn_mfma_f32_16x16x32_bf16(pf[mt], vf, o_acc[mt][dn], 0, 0, 0);
      }
    }
    __syncthreads();
  }

  // epilogue: normalize + store bf16 [16384][1024]
#pragma unroll
  for (int mt = 0; mt < 2; mt++)
#pragma unroll
    for (int dn = 0; dn < 4; dn++)
#pragma unroll
      for (int r = 0; r < 4; r++) {
        const float v = o_acc[mt][dn][r] / l_run[mt][r];
        const int row = rowbase + mt * 16 + fhi * 4 + r;
        O[(size_t)row * DIMC + h * 64 + dn * 16 + fr] = f2bf(v);
      }
}

// ---------------- launch ----------------

extern "C" void kernel_launch(void* const* d_in, const int* in_sizes, int n_in,
                              void* d_out, int out_size, void* d_ws, size_t ws_size,
                              hipStream_t stream) {
  const float* x      = (const float*)d_in[0];
  const float* ctx    = (const float*)d_in[1];
  const int*   cmask  = (const int*)d_in[2];
  const float* q_w    = (const float*)d_in[3];
  const float* q_b    = (const float*)d_in[4];
  const float* kv_w   = (const float*)d_in[5];
  const float* kv_b   = (const float*)d_in[6];
  const float* proj_w = (const float*)d_in[7];
  const float* proj_b = (const float*)d_in[8];
  float* out = (float*)d_out;

  char* ws = (char*)d_ws;
  size_t off = 0;
  auto alloc = [&](size_t bytes) {
    void* p = ws + off;
    off += (bytes + 255) & ~(size_t)255;
    return p;
  };
  u16* x_bf   = (u16*)alloc((size_t)16384 * 1024 * 2);
  u16* ctx_bf = (u16*)alloc((size_t)2048 * 1024 * 2);
  u16* qwT    = (u16*)alloc((size_t)1024 * 1024 * 2);
  u16* kvwT   = (u16*)alloc((size_t)2048 * 1024 * 2);
  u16* pwT    = (u16*)alloc((size_t)1024 * 1024 * 2);
  u16* Qb     = (u16*)alloc((size_t)16384 * 1024 * 2);
  u16* Kbuf   = (u16*)alloc((size_t)64 * 512 * 64 * 2);
  u16* VTbuf  = (u16*)alloc((size_t)64 * 64 * 512 * 2);
  u16* Ob     = (u16*)alloc((size_t)16384 * 1024 * 2);
  float* maskf = (float*)alloc((size_t)NB * NS * 4);

  // conversions
  cvt_kernel<<<2048, 256, 0, stream>>>(x, x_bf, 16777216 / 4);
  cvt_kernel<<<512, 256, 0, stream>>>(ctx, ctx_bf, 2097152 / 4);
  transpose_cvt_kernel<<<dim3(32, 32), 256, 0, stream>>>(q_w, qwT, 1024, 1024);
  transpose_cvt_kernel<<<dim3(64, 32), 256, 0, stream>>>(kv_w, kvwT, 1024, 2048);
  transpose_cvt_kernel<<<dim3(32, 32), 256, 0, stream>>>(proj_w, pwT, 1024, 1024);
  mask_kernel<<<8, 256, 0, stream>>>(cmask, maskf, NB * NS);

  // Q = x @ q_w + q_b  (bf16 out)
  gemm_bt<0><<<dim3(8, 128), 256, 0, stream>>>(x_bf, qwT, q_b, Qb, nullptr, 16384, 1024, 1024);
  // KV = ctx @ kv_w + kv_b  (scatter to K / V^T)
  gemm_bt<1><<<dim3(16, 16), 256, 0, stream>>>(ctx_bf, kvwT, kv_b, Kbuf, VTbuf, 2048, 2048, 1024);
  // attention
  attn_kernel<<<dim3(32, 64), 256, 0, stream>>>(Qb, Kbuf, VTbuf, maskf, Ob);
  // out = O @ proj_w + proj_b (f32)
  gemm_bt<2><<<dim3(8, 128), 256, 0, stream>>>(Ob, pwT, proj_b, out, nullptr, 16384, 1024, 1024);
}